// Round 2
// baseline (1964.469 us; speedup 1.0000x reference)
//
#include <hip/hip_runtime.h>

#define D_MODEL 1024
#define NHEAD   16
#define HDIM    64
#define DFF_    4096
#define TM_     512
#define TA_     512
#define BATCH   32
#define NTOK    (TM_ * BATCH)   // 16384 tokens
#define NBEATS_ 64

typedef __bf16 bfv8 __attribute__((ext_vector_type(8)));
typedef float  f32x4 __attribute__((ext_vector_type(4)));
typedef unsigned short u16x8 __attribute__((ext_vector_type(8)));
typedef unsigned short u16x4 __attribute__((ext_vector_type(4)));

__device__ __forceinline__ unsigned short f2bf(float f) {
  union { float f; unsigned u; } v; v.f = f;
  unsigned r = v.u + 0x7fffu + ((v.u >> 16) & 1u);   // RNE
  return (unsigned short)(r >> 16);
}
__device__ __forceinline__ float bf2f(unsigned short h) {
  union { unsigned u; float f; } v; v.u = ((unsigned)h) << 16;
  return v.f;
}

// ---------------------------------------------------------------- fallback (ws too small diagnostic)
__global__ __launch_bounds__(256) void copy_f32(const float* __restrict__ in, float* __restrict__ out) {
  long i = ((long)blockIdx.x * 256 + threadIdx.x) * 4;
  *(float4*)(out + i) = *(const float4*)(in + i);
}

// ---------------------------------------------------------------- convert
__global__ __launch_bounds__(256) void cvt_f32_bf16(
    const float* __restrict__ in, unsigned short* __restrict__ out) {
  long i = ((long)blockIdx.x * 256 + threadIdx.x) * 4;
  float4 v = *(const float4*)(in + i);
  u16x4 o = { f2bf(v.x), f2bf(v.y), f2bf(v.z), f2bf(v.w) };
  *(u16x4*)(out + i) = o;
}

// ---------------------------------------------------------------- bias precompute
__global__ __launch_bounds__(512) void build_bias(
    const int* __restrict__ beats, float* __restrict__ bias2d) {
  int ta = threadIdx.x;       // 512
  int tm = blockIdx.x;        // 512
  float m = 0.f;
  for (int i = 0; i < NBEATS_; ++i) {
    int bf = beats[i];
    if (bf == ta) m = fmaxf(m, 2.0f);                       // BW
    if (bf > 0 && bf - 1 == ta) m = fmaxf(m, 1.0f);         // BW/2
    if (bf < TA_ - 1 && bf + 1 == ta) m = fmaxf(m, 1.0f);
  }
  float diff = (float)tm - (float)ta;   // scale = (TA-1)/(TM-1) = 1
  bias2d[tm * TA_ + ta] = -(diff * diff) * (1.0f / 32.0f) + m;  // 2*sigma^2=32
}

// ---------------------------------------------------------------- GEMM (NT): C[M,N] = A[M,K] * B[N,K]^T + bias
// BM=BN=128, BK=32, 256 threads (4 waves, 2x2), acc 4x4 frags of 16x16.
// EPI 0: bf16 store at [row*ldc+col]
// EPI 1: GELU -> bf16 store
// EPI 2: QKV scatter: col<s1 -> Qr (x0.125), col<s2 -> Kr, else -> Vt
#define BK 32
#define ALD 40   // padded LDS leading dim (bf16): breaks bank-conflict stride

template<int EPI>
__global__ __launch_bounds__(256) void gemm_nt(
    const unsigned short* __restrict__ A, const unsigned short* __restrict__ Bw,
    const float* __restrict__ bias, int K,
    unsigned short* __restrict__ outP, int ldc,
    unsigned short* __restrict__ dq, unsigned short* __restrict__ dk,
    unsigned short* __restrict__ dv, int s1, int s2) {
  __shared__ __align__(16) unsigned short As[128 * ALD];
  __shared__ __align__(16) unsigned short Bs[128 * ALD];
  const int tid = threadIdx.x;
  const int wave = tid >> 6, lane = tid & 63;
  const int l15 = lane & 15, l4 = lane >> 4;
  const int wr = wave >> 1, wc = wave & 1;
  const long m0 = (long)blockIdx.x * 128;
  const long n0 = (long)blockIdx.y * 128;
  const int srow = tid >> 2, scol = (tid & 3) * 8;

  f32x4 acc[4][4] = {};

  for (int k0 = 0; k0 < K; k0 += BK) {
    u16x8 va0 = *(const u16x8*)&A [(m0 + srow)      * K + k0 + scol];
    u16x8 va1 = *(const u16x8*)&A [(m0 + 64 + srow) * K + k0 + scol];
    u16x8 vb0 = *(const u16x8*)&Bw[(n0 + srow)      * K + k0 + scol];
    u16x8 vb1 = *(const u16x8*)&Bw[(n0 + 64 + srow) * K + k0 + scol];
    __syncthreads();   // previous iter's LDS reads done
    *(u16x8*)&As[srow        * ALD + scol] = va0;
    *(u16x8*)&As[(64 + srow) * ALD + scol] = va1;
    *(u16x8*)&Bs[srow        * ALD + scol] = vb0;
    *(u16x8*)&Bs[(64 + srow) * ALD + scol] = vb1;
    __syncthreads();
    bfv8 af[4], bf[4];
#pragma unroll
    for (int i = 0; i < 4; ++i)
      af[i] = *(const bfv8*)&As[(wr * 64 + i * 16 + l15) * ALD + l4 * 8];
#pragma unroll
    for (int j = 0; j < 4; ++j)
      bf[j] = *(const bfv8*)&Bs[(wc * 64 + j * 16 + l15) * ALD + l4 * 8];
#pragma unroll
    for (int i = 0; i < 4; ++i)
#pragma unroll
      for (int j = 0; j < 4; ++j)
        acc[i][j] = __builtin_amdgcn_mfma_f32_16x16x32_bf16(af[i], bf[j], acc[i][j], 0, 0, 0);
  }

#pragma unroll
  for (int i = 0; i < 4; ++i)
#pragma unroll
    for (int j = 0; j < 4; ++j) {
      int col = (int)n0 + wc * 64 + j * 16 + l15;
      float bv = bias ? bias[col] : 0.f;
#pragma unroll
      for (int r = 0; r < 4; ++r) {
        int row = (int)m0 + wr * 64 + i * 16 + l4 * 4 + r;
        float v = acc[i][j][r] + bv;
        if (EPI == 0) {
          outP[(long)row * ldc + col] = f2bf(v);
        } else if (EPI == 1) {
          float g = 0.5f * v * (1.0f + erff(v * 0.70710678118654752f));
          outP[(long)row * ldc + col] = f2bf(g);
        } else {
          int t = row >> 5, b = row & 31;          // row = t*32 + b
          if (col < s1) {
            int h = col >> 6, d = col & 63;
            dq[(((long)b * NHEAD + h) * TM_ + t) * HDIM + d] = f2bf(v * 0.125f);
          } else if (col < s2) {
            int c = col - s1, h = c >> 6, d = c & 63;
            dk[(((long)b * NHEAD + h) * TA_ + t) * HDIM + d] = f2bf(v);
          } else {
            int c = col - s2, h = c >> 6, d = c & 63;
            dv[(((long)b * NHEAD + h) * HDIM + d) * TA_ + t] = f2bf(v);
          }
        }
      }
    }
}

// ---------------------------------------------------------------- fused attention
// One block = one (bh, 16 q-rows). Exact softmax (full 512-wide row in LDS).
// Qr: (bh, t, 64) bf16 (pre-scaled 0.125); Kr: (bh, t, 64); Vt: (bh, 64, t).
// Orow out: (t*B+b, h*64+d) bf16.
__global__ __launch_bounds__(256) void attn_fused(
    const unsigned short* __restrict__ Qr, const unsigned short* __restrict__ Kr,
    const unsigned short* __restrict__ Vt, const float* __restrict__ bias2d,
    unsigned short* __restrict__ Orow) {
  __shared__ __align__(16) unsigned short Qs[16][72];
  __shared__ __align__(16) float S[16][513];
  __shared__ __align__(16) unsigned short P[16][520];
  const int q0 = blockIdx.x * 16;
  const int bh = blockIdx.y;
  const int b = bh >> 4, h = bh & 15;
  const int tid = threadIdx.x, wave = tid >> 6, lane = tid & 63;
  const int l15 = lane & 15, l4 = lane >> 4;

  if (tid < 128) {
    int row = tid >> 3, col = (tid & 7) * 8;
    *(u16x8*)&Qs[row][col] = *(const u16x8*)&Qr[((long)bh * TM_ + q0 + row) * HDIM + col];
  }
  __syncthreads();

  // --- scores: wave handles key-cols [wave*128, wave*128+128)
  {
    f32x4 s[8] = {};
#pragma unroll
    for (int k0 = 0; k0 < 64; k0 += 32) {
      bfv8 a = *(const bfv8*)&Qs[l15][k0 + l4 * 8];
#pragma unroll
      for (int f = 0; f < 8; ++f) {
        bfv8 bb = *(const bfv8*)&Kr[((long)bh * TA_ + wave * 128 + f * 16 + l15) * HDIM + k0 + l4 * 8];
        s[f] = __builtin_amdgcn_mfma_f32_16x16x32_bf16(a, bb, s[f], 0, 0, 0);
      }
    }
#pragma unroll
    for (int f = 0; f < 8; ++f)
#pragma unroll
      for (int r = 0; r < 4; ++r) {
        int rr = l4 * 4 + r, cc = wave * 128 + f * 16 + l15;
        float v = s[f][r];
        if (bias2d) v += bias2d[(long)(q0 + rr) * TA_ + cc];
        S[rr][cc] = v;
      }
  }
  __syncthreads();

  // --- softmax: 16 threads per row (exact, full 512 row)
  {
    int r = tid >> 4, j = tid & 15;
    float vals[32];
    float mx = -1e30f;
#pragma unroll
    for (int k = 0; k < 32; ++k) { float v = S[r][k * 16 + j]; vals[k] = v; mx = fmaxf(mx, v); }
#pragma unroll
    for (int off = 1; off < 16; off <<= 1) mx = fmaxf(mx, __shfl_xor(mx, off, 16));
    float sum = 0.f;
#pragma unroll
    for (int k = 0; k < 32; ++k) { float e = __expf(vals[k] - mx); vals[k] = e; sum += e; }
#pragma unroll
    for (int off = 1; off < 16; off <<= 1) sum += __shfl_xor(sum, off, 16);
    float inv = 1.f / sum;
#pragma unroll
    for (int k = 0; k < 32; ++k) P[r][k * 16 + j] = f2bf(vals[k] * inv);
  }
  __syncthreads();

  // --- PV: wave handles d-range [wave*16, wave*16+16)
  {
    f32x4 o = {};
#pragma unroll
    for (int k0 = 0; k0 < 512; k0 += 32) {
      bfv8 a = *(const bfv8*)&P[l15][k0 + l4 * 8];
      bfv8 bb = *(const bfv8*)&Vt[((long)bh * HDIM + wave * 16 + l15) * TA_ + k0 + l4 * 8];
      o = __builtin_amdgcn_mfma_f32_16x16x32_bf16(a, bb, o, 0, 0, 0);
    }
#pragma unroll
    for (int r = 0; r < 4; ++r) {
      int rr = l4 * 4 + r, dd = wave * 16 + l15;
      Orow[((long)(q0 + rr) * BATCH + b) * D_MODEL + h * HDIM + dd] = f2bf(o[r]);
    }
  }
}

// ---------------------------------------------------------------- fused residual + LayerNorm
// y = resid + g*cin ; out = LN(y)*gamma+beta.  cin bf16; resid f32 OR bf16; out f32 and/or bf16.
__global__ __launch_bounds__(256) void ln_fused(
    const unsigned short* __restrict__ cin,
    const float* __restrict__ residf, const unsigned short* __restrict__ residb,
    const float* __restrict__ gamma, const float* __restrict__ beta,
    const float* __restrict__ gate,
    float* __restrict__ out_f32, unsigned short* __restrict__ out_bf16) {
  long row = blockIdx.x;
  int t = threadIdx.x;
  float gf = gate ? tanhf(gate[0]) : 1.0f;
  u16x4 cvb = *(const u16x4*)(cin + row * 1024 + t * 4);
  float c0 = bf2f(cvb[0]), c1 = bf2f(cvb[1]), c2 = bf2f(cvb[2]), c3 = bf2f(cvb[3]);
  float r0, r1, r2, r3;
  if (residf) {
    float4 rv = *(const float4*)(residf + row * 1024 + t * 4);
    r0 = rv.x; r1 = rv.y; r2 = rv.z; r3 = rv.w;
  } else {
    u16x4 rv = *(const u16x4*)(residb + row * 1024 + t * 4);
    r0 = bf2f(rv[0]); r1 = bf2f(rv[1]); r2 = bf2f(rv[2]); r3 = bf2f(rv[3]);
  }
  float y0 = r0 + gf * c0, y1 = r1 + gf * c1, y2 = r2 + gf * c2, y3 = r3 + gf * c3;
  float s = y0 + y1 + y2 + y3;
  float q = y0 * y0 + y1 * y1 + y2 * y2 + y3 * y3;
#pragma unroll
  for (int off = 32; off; off >>= 1) { s += __shfl_xor(s, off); q += __shfl_xor(q, off); }
  __shared__ float sw[4], qw[4];
  int wave = t >> 6;
  if ((t & 63) == 0) { sw[wave] = s; qw[wave] = q; }
  __syncthreads();
  s = sw[0] + sw[1] + sw[2] + sw[3];
  q = qw[0] + qw[1] + qw[2] + qw[3];
  float mean = s * (1.0f / 1024.0f);
  float var = q * (1.0f / 1024.0f) - mean * mean;
  float rstd = rsqrtf(var + 1e-5f);
  float4 g4 = *(const float4*)(gamma + t * 4);
  float4 b4 = *(const float4*)(beta + t * 4);
  float o0 = (y0 - mean) * rstd * g4.x + b4.x;
  float o1 = (y1 - mean) * rstd * g4.y + b4.y;
  float o2 = (y2 - mean) * rstd * g4.z + b4.z;
  float o3 = (y3 - mean) * rstd * g4.w + b4.w;
  if (out_f32) {
    float4 o = { o0, o1, o2, o3 };
    *(float4*)(out_f32 + row * 1024 + t * 4) = o;
  }
  if (out_bf16) {
    u16x4 ob = { f2bf(o0), f2bf(o1), f2bf(o2), f2bf(o3) };
    *(u16x4*)(out_bf16 + row * 1024 + t * 4) = ob;
  }
}

// ---------------------------------------------------------------- host
static inline char* wsa(char*& p, size_t bytes) {
  char* r = p;
  p += (bytes + 255) & ~(size_t)255;
  return r;
}

extern "C" void kernel_launch(void* const* d_in, const int* in_sizes, int n_in,
                              void* d_out, int out_size, void* d_ws, size_t ws_size,
                              hipStream_t stream) {
  const float* src      = (const float*)d_in[0];
  const float* audio    = (const float*)d_in[1];
  const int*   beats    = (const int*)d_in[2];
  const float* sa_in_w  = (const float*)d_in[3];
  const float* sa_in_b  = (const float*)d_in[4];
  const float* sa_out_w = (const float*)d_in[5];
  const float* sa_out_b = (const float*)d_in[6];
  const float* ca_in_w  = (const float*)d_in[7];
  const float* ca_in_b  = (const float*)d_in[8];
  const float* ca_out_w = (const float*)d_in[9];
  const float* ca_out_b = (const float*)d_in[10];
  const float* gate     = (const float*)d_in[11];
  const float* n1_g     = (const float*)d_in[12];
  const float* n1_b     = (const float*)d_in[13];
  const float* nc_g     = (const float*)d_in[14];
  const float* nc_b     = (const float*)d_in[15];
  const float* n2_g     = (const float*)d_in[16];
  const float* n2_b     = (const float*)d_in[17];
  const float* l1_w     = (const float*)d_in[18];
  const float* l1_b     = (const float*)d_in[19];
  const float* l2_w     = (const float*)d_in[20];
  const float* l2_b     = (const float*)d_in[21];
  float* out = (float*)d_out;
  (void)in_sizes; (void)n_in; (void)out_size;

  // ---- workspace plan: 225 MiB total (aggressive aliasing)
  const size_t NEEDED = (size_t)236000000;
  if (ws_size < NEEDED) {
    // diagnostic fallback: clean absmax fail instead of OOB crash
    copy_f32<<<dim3(NTOK), dim3(256), 0, stream>>>(src, out);
    return;
  }

  char* p = (char*)d_ws;
  float*          bias2d = (float*)         wsa(p, (size_t)TM_ * TA_ * 4);                 // 1 MB
  unsigned short* wsaiw  = (unsigned short*)wsa(p, (size_t)3 * D_MODEL * D_MODEL * 2);     // 6
  unsigned short* wsaow  = (unsigned short*)wsa(p, (size_t)D_MODEL * D_MODEL * 2);         // 2
  unsigned short* wcaiw  = (unsigned short*)wsa(p, (size_t)3 * D_MODEL * D_MODEL * 2);     // 6
  unsigned short* wcaow  = (unsigned short*)wsa(p, (size_t)D_MODEL * D_MODEL * 2);         // 2
  unsigned short* wl1    = (unsigned short*)wsa(p, (size_t)DFF_ * D_MODEL * 2);            // 8
  unsigned short* wl2    = (unsigned short*)wsa(p, (size_t)D_MODEL * DFF_ * 2);            // 8
  unsigned short* srcb   = (unsigned short*)wsa(p, (size_t)NTOK * D_MODEL * 2);            // 32
  unsigned short* audb   = (unsigned short*)wsa(p, (size_t)NTOK * D_MODEL * 2);            // 32
  // H1 (128 MiB) overlays [Qr | Kr | Vt | x1b] — keep these four contiguous:
  unsigned short* Qr     = (unsigned short*)wsa(p, (size_t)NTOK * D_MODEL * 2);            // 32
  unsigned short* Kr     = (unsigned short*)wsa(p, (size_t)NTOK * D_MODEL * 2);            // 32
  unsigned short* Vt     = (unsigned short*)wsa(p, (size_t)NTOK * D_MODEL * 2);            // 32
  unsigned short* x1b    = (unsigned short*)wsa(p, (size_t)NTOK * D_MODEL * 2);            // 32
  unsigned short* Orow   = srcb;   // srcb dead after QKV GEMM
  unsigned short* C1     = Vt;     // ln input; Vt dead when written (after each attn)
  unsigned short* x2b    = audb;   // audb dead after cross-KV GEMM
  unsigned short* H1     = Qr;     // FFN hidden (16384x4096 bf16 = 128 MiB over Qr..x1b)
  unsigned short* C2     = srcb;   // FFN out; Orow dead after cross out-proj

  // ---- bias + converts
  build_bias<<<dim3(TM_), dim3(TA_), 0, stream>>>(beats, bias2d);
  cvt_f32_bf16<<<dim3((NTOK * D_MODEL) / 1024), dim3(256), 0, stream>>>(src, srcb);
  cvt_f32_bf16<<<dim3((NTOK * D_MODEL) / 1024), dim3(256), 0, stream>>>(audio, audb);
  cvt_f32_bf16<<<dim3((3 * D_MODEL * D_MODEL) / 1024), dim3(256), 0, stream>>>(sa_in_w, wsaiw);
  cvt_f32_bf16<<<dim3((D_MODEL * D_MODEL) / 1024), dim3(256), 0, stream>>>(sa_out_w, wsaow);
  cvt_f32_bf16<<<dim3((3 * D_MODEL * D_MODEL) / 1024), dim3(256), 0, stream>>>(ca_in_w, wcaiw);
  cvt_f32_bf16<<<dim3((D_MODEL * D_MODEL) / 1024), dim3(256), 0, stream>>>(ca_out_w, wcaow);
  cvt_f32_bf16<<<dim3((DFF_ * D_MODEL) / 1024), dim3(256), 0, stream>>>(l1_w, wl1);
  cvt_f32_bf16<<<dim3((D_MODEL * DFF_) / 1024), dim3(256), 0, stream>>>(l2_w, wl2);

  // ---- self-attention: QKV GEMM scatters straight into Qr/Kr/Vt
  gemm_nt<2><<<dim3(NTOK / 128, 24), dim3(256), 0, stream>>>(
      srcb, wsaiw, sa_in_b, 1024, nullptr, 0, Qr, Kr, Vt, 1024, 2048);
  attn_fused<<<dim3(TM_ / 16, BATCH * NHEAD), dim3(256), 0, stream>>>(Qr, Kr, Vt, nullptr, Orow);
  gemm_nt<0><<<dim3(NTOK / 128, 8), dim3(256), 0, stream>>>(
      Orow, wsaow, sa_out_b, 1024, C1, 1024, nullptr, nullptr, nullptr, 0, 0);
  ln_fused<<<dim3(NTOK), dim3(256), 0, stream>>>(C1, src, nullptr, n1_g, n1_b, nullptr, nullptr, x1b);

  // ---- cross-attention
  gemm_nt<2><<<dim3(NTOK / 128, 8), dim3(256), 0, stream>>>(
      x1b, wcaiw, ca_in_b, 1024, nullptr, 0, Qr, Kr, Vt, 1024, 1024);          // all cols -> Q
  gemm_nt<2><<<dim3(NTOK / 128, 16), dim3(256), 0, stream>>>(
      audb, wcaiw + (size_t)D_MODEL * D_MODEL, ca_in_b + 1024, 1024,
      nullptr, 0, Qr, Kr, Vt, 0, 1024);                                        // K then V
  attn_fused<<<dim3(TM_ / 16, BATCH * NHEAD), dim3(256), 0, stream>>>(Qr, Kr, Vt, bias2d, Orow);
  gemm_nt<0><<<dim3(NTOK / 128, 8), dim3(256), 0, stream>>>(
      Orow, wcaow, ca_out_b, 1024, C1, 1024, nullptr, nullptr, nullptr, 0, 0);
  ln_fused<<<dim3(NTOK), dim3(256), 0, stream>>>(C1, nullptr, x1b, nc_g, nc_b, gate, nullptr, x2b);

  // ---- FFN
  gemm_nt<1><<<dim3(NTOK / 128, 32), dim3(256), 0, stream>>>(
      x2b, wl1, l1_b, 1024, H1, DFF_, nullptr, nullptr, nullptr, 0, 0);
  gemm_nt<0><<<dim3(NTOK / 128, 8), dim3(256), 0, stream>>>(
      H1, wl2, l2_b, DFF_, C2, 1024, nullptr, nullptr, nullptr, 0, 0);
  ln_fused<<<dim3(NTOK), dim3(256), 0, stream>>>(C2, nullptr, x2b, n2_g, n2_b, nullptr, out, nullptr);
}